// Round 1
// baseline (1534.707 us; speedup 1.0000x reference)
//
#include <hip/hip_runtime.h>
#include <stdint.h>

#define V_N    4096
#define NNZ_N  36864
#define S_N    216        // X*Y*Z = 6*6*6
#define ST_TOT 27         // S_N / 8
#define PLANES 256        // K * FIN

typedef float  f32x4 __attribute__((ext_vector_type(4)));
typedef short  s16x4 __attribute__((ext_vector_type(4)));
typedef short  s16x8 __attribute__((ext_vector_type(8)));

static __device__ __forceinline__ unsigned short f2bf(float f){
    union { float f; unsigned u; } x; x.f = f;
    unsigned r = x.u + 0x7FFFu + ((x.u >> 16) & 1u);   // round-to-nearest-even
    return (unsigned short)(r >> 16);
}
static __device__ __forceinline__ unsigned packbf(float lo, float hi){
    return (unsigned)f2bf(lo) | ((unsigned)f2bf(hi) << 16);
}
#define BLO(u) __uint_as_float((u) << 16)
#define BHI(u) __uint_as_float((u) & 0xFFFF0000u)

// ---------------- CSR build ----------------
__global__ void k_hist(const int* __restrict__ rows, int* __restrict__ counts){
    int e = blockIdx.x * 256 + threadIdx.x;
    if (e < NNZ_N) atomicAdd(&counts[rows[e]], 1);
}
__global__ void k_deghist(const int* __restrict__ counts, int* __restrict__ dh){
    int v = blockIdx.x * 256 + threadIdx.x;
    if (v < V_N){ int d = counts[v]; if (d > 63) d = 63; atomicAdd(&dh[d], 1); }
}
__global__ void k_degscan(const int* __restrict__ dh, int* __restrict__ dhoff){
    if (threadIdx.x == 0){ int s = 0; for (int i = 0; i < 64; ++i){ dhoff[i] = s; s += dh[i]; } }
}
__global__ void k_sortrows(const int* __restrict__ counts, int* __restrict__ dhoff,
                           int* __restrict__ row_order, int* __restrict__ sp,
                           int* __restrict__ counts2){
    int v = blockIdx.x * 256 + threadIdx.x;
    if (v < V_N){
        int d = counts[v]; int db = d > 63 ? 63 : d;
        int pos = atomicAdd(&dhoff[db], 1);
        row_order[pos] = v; sp[v] = pos; counts2[pos] = d;
    }
}
__global__ void k_scan(const int* __restrict__ counts2, int* __restrict__ row_ptr2,
                       int* __restrict__ cursor2){
    __shared__ int ss[1024];
    int t = threadIdx.x;
    int4 c = ((const int4*)counts2)[t];
    int tot = c.x + c.y + c.z + c.w;
    ss[t] = tot; __syncthreads();
    for (int off = 1; off < 1024; off <<= 1){
        int vv = 0; if (t >= off) vv = ss[t - off];
        __syncthreads();
        if (t >= off) ss[t] += vv;
        __syncthreads();
    }
    int excl = ss[t] - tot;
    int4 rp; rp.x = excl; rp.y = excl + c.x; rp.z = rp.y + c.y; rp.w = rp.z + c.z;
    ((int4*)row_ptr2)[t] = rp;
    ((int4*)cursor2)[t]  = rp;
    if (t == 1023) row_ptr2[4096] = excl + tot;
}
__global__ void k_fill(const int* __restrict__ rows, const int* __restrict__ cols,
                       const float* __restrict__ vals, const int* __restrict__ sp,
                       int* __restrict__ cursor2, unsigned* __restrict__ csr){
    int e = blockIdx.x * 256 + threadIdx.x;
    if (e < NNZ_N){
        int r = rows[e];
        int pos = atomicAdd(&cursor2[sp[r]], 1);
        csr[pos] = (unsigned)(cols[e] & 0xFFFF) | ((unsigned)f2bf(vals[e]) << 16);
    }
}
// W packed into MFMA B-fragment order: slot=(ki*2+nh)*64+lane, elem j ->
// W[p = ki*32 + (lane>>4)*8 + j][fo = nh*16 + (lane&15)]
__global__ void k_wtab(const float* __restrict__ w, unsigned short* __restrict__ wtab){
    int idx = blockIdx.x * 256 + threadIdx.x;   // 0..8191
    int slot = idx >> 3, j = idx & 7;
    int ki = slot >> 7, nh = (slot >> 6) & 1, l = slot & 63;
    int p  = ki * 32 + ((l >> 4) << 3) + j;
    int fo = nh * 16 + (l & 15);
    wtab[idx] = f2bf(w[p * 32 + fo]);
}

// ---------------- Phase A: LDS-resident Chebyshev recurrence ----------------
// block = (f, s8-tile). LDS holds T_{k-1}[4096][8] bf16; T_{k-2} for own rows in regs.
__global__ __launch_bounds__(1024, 4) void k_phaseA(
    const float* __restrict__ in, const int* __restrict__ row_ptr2,
    const int* __restrict__ row_order, const unsigned* __restrict__ csr,
    uint4* __restrict__ basis, int tiles_c, int st0)
{
    __shared__ uint4 T4[V_N];        // 64 KB
    int f   = blockIdx.x & 31;
    int stl = blockIdx.x >> 5;
    int st_g = st0 + stl;
    int t = threadIdx.x;

    // coalesced load of T0, write to LDS + basis plane p=f (k=0)
    #pragma unroll
    for (int rr = 0; rr < 4; ++rr){
        int v = t + rr * 1024;
        const float* src = in + ((size_t)f * V_N + v) * S_N + st_g * 8;
        float4 a = ((const float4*)src)[0];
        float4 b = ((const float4*)src)[1];
        uint4 q;
        q.x = packbf(a.x, a.y); q.y = packbf(a.z, a.w);
        q.z = packbf(b.x, b.y); q.w = packbf(b.z, b.w);
        T4[v] = q;
        basis[((size_t)(f * tiles_c + stl)) * V_N + v] = q;
    }
    __syncthreads();

    // this thread owns sorted rows t*4 .. t*4+3 (contiguous in CSR)
    int vr[4]; int rp[5];
    #pragma unroll
    for (int rr = 0; rr < 4; ++rr) vr[rr] = row_order[t * 4 + rr];
    #pragma unroll
    for (int i = 0; i < 5; ++i) rp[i] = row_ptr2[t * 4 + i];

    uint4 tm2[4];
    #pragma unroll
    for (int rr = 0; rr < 4; ++rr) tm2[rr] = T4[vr[rr]];   // T0 own rows

    for (int k = 1; k < 8; ++k){
        uint4 nst[4];
        int e = rp[0];
        #pragma unroll
        for (int rr = 0; rr < 4; ++rr){
            float a0=0,a1=0,a2=0,a3=0,a4=0,a5=0,a6=0,a7=0;
            int eend = rp[rr + 1];
            for (; e < eend; ++e){
                unsigned cv = csr[e];
                uint4 qq = T4[cv & 0xFFFFu];
                float val = __uint_as_float(cv & 0xFFFF0000u);
                a0 = fmaf(val, BLO(qq.x), a0);  a1 = fmaf(val, BHI(qq.x), a1);
                a2 = fmaf(val, BLO(qq.y), a2);  a3 = fmaf(val, BHI(qq.y), a3);
                a4 = fmaf(val, BLO(qq.z), a4);  a5 = fmaf(val, BHI(qq.z), a5);
                a6 = fmaf(val, BLO(qq.w), a6);  a7 = fmaf(val, BHI(qq.w), a7);
            }
            if (k > 1){
                a0 = 2.f*a0 - BLO(tm2[rr].x);  a1 = 2.f*a1 - BHI(tm2[rr].x);
                a2 = 2.f*a2 - BLO(tm2[rr].y);  a3 = 2.f*a3 - BHI(tm2[rr].y);
                a4 = 2.f*a4 - BLO(tm2[rr].z);  a5 = 2.f*a5 - BHI(tm2[rr].z);
                a6 = 2.f*a6 - BLO(tm2[rr].w);  a7 = 2.f*a7 - BHI(tm2[rr].w);
            }
            uint4 nq;
            nq.x = packbf(a0, a1); nq.y = packbf(a2, a3);
            nq.z = packbf(a4, a5); nq.w = packbf(a6, a7);
            nst[rr] = nq;
            basis[((size_t)((k * 32 + f) * tiles_c + stl)) * V_N + vr[rr]] = nq;
        }
        #pragma unroll
        for (int rr = 0; rr < 4; ++rr) tm2[rr] = T4[vr[rr]];   // T_{k-1} own rows
        __syncthreads();
        #pragma unroll
        for (int rr = 0; rr < 4; ++rr) T4[vr[rr]] = nst[rr];   // LDS <- T_k
        __syncthreads();
    }
}

// ---------------- Phase B: projection GEMM (MFMA bf16) ----------------
// out[fo][v][s] = sum_p basis[p][r] * W[p][fo] + bias[fo],  r=(st,v,sl), 32 rows/WG
__global__ __launch_bounds__(256, 4) void k_phaseB(
    const uint4* __restrict__ basis, const uint4* __restrict__ wtab,
    const float* __restrict__ bias, float* __restrict__ out,
    int tiles_c, int st0)
{
    __shared__ uint4 AW[2048];   // A-perm: [0..1023] (16KB), W: [1024..2047] (16KB)
    int t = threadIdx.x;
    int tile = blockIdx.x;
    int PLANE16 = tiles_c * V_N;

    // stage A tile (permuted for ds_read_b64_tr_b16) + W table
    #pragma unroll
    for (int it = 0; it < 4; ++it){
        int b = t + it * 256;
        int msub = (b >> 9) & 1, ki = (b >> 6) & 7, h = (b >> 5) & 1;
        int g = (b >> 3) & 3, j = (b >> 1) & 3, ch = b & 1;
        int p = ki * 32 + g * 8 + h * 4 + j;
        AW[b] = basis[(size_t)p * PLANE16 + tile * 4 + msub * 2 + ch];
        AW[1024 + b] = wtab[b];
    }
    __syncthreads();

    int lane = t & 63, w = t >> 6;
    int msub = w & 1, nh = w >> 1;
    unsigned abase = (unsigned)(size_t)(&AW[0]) + msub * 8192 + (lane << 3);

    f32x4 acc = {0.f, 0.f, 0.f, 0.f};
    #pragma unroll
    for (int ki = 0; ki < 8; ++ki){
        s16x4 x0, x1;
        unsigned addr = abase + ki * 1024;
        asm volatile("ds_read_b64_tr_b16 %0, %2\n\t"
                     "ds_read_b64_tr_b16 %1, %2 offset:512\n\t"
                     "s_waitcnt lgkmcnt(0)"
                     : "=&v"(x0), "=&v"(x1) : "v"(addr));
        __builtin_amdgcn_sched_barrier(0);
        s16x8 af;
        af[0]=x0[0]; af[1]=x0[1]; af[2]=x0[2]; af[3]=x0[3];
        af[4]=x1[0]; af[5]=x1[1]; af[6]=x1[2]; af[7]=x1[3];
        s16x8 bfr = *(const s16x8*)&AW[1024 + (ki * 2 + nh) * 64 + lane];
        acc = __builtin_amdgcn_mfma_f32_16x16x32_bf16(af, bfr, acc, 0, 0, 0);
    }

    int rowbase = tile * 32;
    int stl = rowbase >> 15;
    int r0 = (rowbase & 32767) + msub * 16 + ((lane >> 4) << 2);
    int v = r0 >> 3;
    int sl0 = r0 & 7;
    int fo = nh * 16 + (lane & 15);
    float bs = bias[fo];
    float4 o; o.x = acc[0] + bs; o.y = acc[1] + bs; o.z = acc[2] + bs; o.w = acc[3] + bs;
    *(float4*)(out + ((size_t)fo * V_N + v) * S_N + (size_t)(st0 + stl) * 8 + sl0) = o;
}

// ---------------- host ----------------
extern "C" void kernel_launch(void* const* d_in, const int* in_sizes, int n_in,
                              void* d_out, int out_size, void* d_ws, size_t ws_size,
                              hipStream_t stream)
{
    const float* inp  = (const float*)d_in[0];
    const float* wgt  = (const float*)d_in[1];
    const float* bias = (const float*)d_in[2];
    const float* vals = (const float*)d_in[3];
    const int*   rows = (const int*)d_in[4];
    const int*   cols = (const int*)d_in[5];
    float* out = (float*)d_out;

    char* ws = (char*)d_ws;
    size_t o = 0;
    auto alloc = [&](size_t bytes) -> void* {
        void* p = ws + o; o = (o + bytes + 255) & ~(size_t)255; return p;
    };
    int* counts    = (int*)alloc(4096 * 4);
    int* dh        = (int*)alloc(64 * 4);
    int* dhoff     = (int*)alloc(64 * 4);
    int* row_order = (int*)alloc(4096 * 4);
    int* sp        = (int*)alloc(4096 * 4);
    int* counts2   = (int*)alloc(4096 * 4);
    int* row_ptr2  = (int*)alloc(4097 * 4);
    int* cursor2   = (int*)alloc(4096 * 4);
    unsigned* csr  = (unsigned*)alloc(NNZ_N * 4);
    uint4* wtab    = (uint4*)alloc(8192 * 2);
    size_t used = o;

    size_t per_tile = (size_t)PLANES * V_N * 16;   // 16.78 MB per s8-tile
    size_t avail = (ws_size > used) ? (ws_size - used) : 0;
    int tiles_c = (int)(avail / per_tile);
    if (tiles_c > ST_TOT) tiles_c = ST_TOT;
    if (tiles_c < 1) tiles_c = 1;
    uint4* basis = (uint4*)alloc(per_tile * tiles_c);

    hipMemsetAsync(counts, 0, 4096 * 4, stream);
    hipMemsetAsync(dh, 0, 64 * 4, stream);
    k_hist    <<<144, 256, 0, stream>>>(rows, counts);
    k_deghist <<<16, 256, 0, stream>>>(counts, dh);
    k_degscan <<<1, 64, 0, stream>>>(dh, dhoff);
    k_sortrows<<<16, 256, 0, stream>>>(counts, dhoff, row_order, sp, counts2);
    k_scan    <<<1, 1024, 0, stream>>>(counts2, row_ptr2, cursor2);
    k_fill    <<<144, 256, 0, stream>>>(rows, cols, vals, sp, cursor2, csr);
    k_wtab    <<<32, 256, 0, stream>>>(wgt, (unsigned short*)wtab);

    for (int st0 = 0; st0 < ST_TOT; st0 += tiles_c){
        int tc = ST_TOT - st0; if (tc > tiles_c) tc = tiles_c;
        k_phaseA<<<32 * tc, 1024, 0, stream>>>(inp, row_ptr2, row_order, csr, basis, tc, st0);
        k_phaseB<<<tc * 1024, 256, 0, stream>>>(basis, wtab, bias, out, tc, st0);
    }
}

// Round 2
// 826.773 us; speedup vs baseline: 1.8563x; 1.8563x over previous
//
#include <hip/hip_runtime.h>
#include <stdint.h>

#define V_N    4096
#define NNZ_N  36864
#define S_N    216        // X*Y*Z = 6*6*6
#define ST_TOT 27         // S_N / 8
#define PLANES 256        // K * FIN

typedef float  f32x4 __attribute__((ext_vector_type(4)));
typedef short  s16x4 __attribute__((ext_vector_type(4)));
typedef short  s16x8 __attribute__((ext_vector_type(8)));

static __device__ __forceinline__ unsigned short f2bf(float f){
    union { float f; unsigned u; } x; x.f = f;
    unsigned r = x.u + 0x7FFFu + ((x.u >> 16) & 1u);   // round-to-nearest-even
    return (unsigned short)(r >> 16);
}
static __device__ __forceinline__ unsigned packbf(float lo, float hi){
    return (unsigned)f2bf(lo) | ((unsigned)f2bf(hi) << 16);
}
#define BLO(u) __uint_as_float((u) << 16)
#define BHI(u) __uint_as_float((u) & 0xFFFF0000u)

// ---------------- graph prep ----------------
__global__ void k_hist(const int* __restrict__ rows, int* __restrict__ counts){
    int e = blockIdx.x * 256 + threadIdx.x;
    if (e < NNZ_N) atomicAdd(&counts[rows[e]], 1);
}
__global__ void k_deghist(const int* __restrict__ counts, int* __restrict__ dh){
    int v = blockIdx.x * 256 + threadIdx.x;
    if (v < V_N){ int d = counts[v]; if (d > 63) d = 63; atomicAdd(&dh[d], 1); }
}
__global__ void k_degscan(const int* __restrict__ dh, int* __restrict__ dhoff){
    if (threadIdx.x == 0){ int s = 0; for (int i = 0; i < 64; ++i){ dhoff[i] = s; s += dh[i]; } }
}
__global__ void k_sortrows(const int* __restrict__ counts, int* __restrict__ dhoff,
                           int* __restrict__ row_order, int* __restrict__ sp,
                           int* __restrict__ counts2){
    int v = blockIdx.x * 256 + threadIdx.x;
    if (v < V_N){
        int d = counts[v]; int db = d > 63 ? 63 : d;
        int pos = atomicAdd(&dhoff[db], 1);
        row_order[pos] = v; sp[v] = pos; counts2[pos] = d;
    }
}
// 64 groups of 64 sorted rows: gcnt[g] = max degree in group (clamped 64),
// goff[g] = exclusive scan of gcnt*64 (ELL slots)
__global__ void k_goff(const int* __restrict__ counts2, int* __restrict__ gcnt,
                       int* __restrict__ goff){
    if (threadIdx.x == 0){
        int off = 0;
        for (int g = 0; g < 64; ++g){
            int d = counts2[g * 64 + 63];
            if (d > 64) d = 64;
            gcnt[g] = d; goff[g] = off; off += d * 64;
        }
    }
}
// lane-transposed zero-padded ELL: slot(g, i, lane) = goff[g] + i*64 + lane
__global__ void k_fillell(const int* __restrict__ rows, const int* __restrict__ cols,
                          const float* __restrict__ vals, const int* __restrict__ sp,
                          const int* __restrict__ gcnt, const int* __restrict__ goff,
                          int* __restrict__ rcur, unsigned* __restrict__ ell){
    int e = blockIdx.x * 256 + threadIdx.x;
    if (e < NNZ_N){
        int r = rows[e]; int s = sp[r]; int g = s >> 6; int l = s & 63;
        int i = atomicAdd(&rcur[r], 1);
        if (i < gcnt[g])
            ell[goff[g] + i * 64 + l] =
                (unsigned)(cols[e] & 0xFFFF) | ((unsigned)f2bf(vals[e]) << 16);
    }
}
// W packed into MFMA B-fragment order: slot=(ki*2+nh)*64+lane, elem j ->
// W[p = ki*32 + (lane>>4)*8 + j][fo = nh*16 + (lane&15)]
__global__ void k_wtab(const float* __restrict__ w, unsigned short* __restrict__ wtab){
    int idx = blockIdx.x * 256 + threadIdx.x;   // 0..8191
    int slot = idx >> 3, j = idx & 7;
    int ki = slot >> 7, nh = (slot >> 6) & 1, l = slot & 63;
    int p  = ki * 32 + ((l >> 4) << 3) + j;
    int fo = nh * 16 + (l & 15);
    wtab[idx] = f2bf(w[p * 32 + fo]);
}

// b-index inside a 32-row tile's 1024-uint4 staged block, for plane p, v
// b = msub*512 + ki*64 + h*32 + g*8 + j*2 + ch  (ki=p>>5, g=(p>>3)&3, h=(p>>2)&1, j=p&3)
// msub=(v>>1)&1, ch=v&1 ; tile32 = st_local*1024 + (v>>2)

// ---------------- Phase A: LDS-resident Chebyshev recurrence ----------------
__global__ __launch_bounds__(1024, 8) void k_phaseA(
    const float* __restrict__ in, const int* __restrict__ row_order,
    const int* __restrict__ goff, const int* __restrict__ gcnt,
    const unsigned* __restrict__ ell, uint4* __restrict__ basisT, int st0)
{
    __shared__ uint4 T4[V_N];        // 64 KB
    int f   = blockIdx.x & 31;
    int stl = blockIdx.x >> 5;
    int st_g = st0 + stl;
    int t = threadIdx.x;
    int bb_f = (((f >> 2) & 1) << 5) + (((f >> 3) & 3) << 3) + ((f & 3) << 1);

    // T0: coalesced load, write LDS + basisT (k=0 planes)
    #pragma unroll
    for (int rr = 0; rr < 4; ++rr){
        int v = t + rr * 1024;
        const float* src = in + ((size_t)f * V_N + v) * S_N + st_g * 8;
        float4 a = ((const float4*)src)[0];
        float4 b = ((const float4*)src)[1];
        uint4 q;
        q.x = packbf(a.x, a.y); q.y = packbf(a.z, a.w);
        q.z = packbf(b.x, b.y); q.w = packbf(b.z, b.w);
        T4[v] = q;
        basisT[(size_t)(stl * 1024 + (v >> 2)) * 1024
               + (((v >> 1) & 1) << 9) + bb_f + (v & 1)] = q;
    }
    __syncthreads();

    int w = t >> 6, lane = t & 63;
    int vr[4], gba[4], gcn[4];
    #pragma unroll
    for (int rr = 0; rr < 4; ++rr){
        int g = w * 4 + rr;
        vr[rr]  = row_order[g * 64 + lane];
        gba[rr] = goff[g] + lane;
        gcn[rr] = __builtin_amdgcn_readfirstlane(gcnt[g]);
    }
    uint4 tm2[4];
    #pragma unroll
    for (int rr = 0; rr < 4; ++rr) tm2[rr] = T4[vr[rr]];   // T0 own rows

    for (int k = 1; k < 8; ++k){
        uint4 nst[4];
        #pragma unroll
        for (int rr = 0; rr < 4; ++rr){
            float a0=0,a1=0,a2=0,a3=0,a4=0,a5=0,a6=0,a7=0;
            const unsigned* ep = ell + gba[rr];
            int cnt = gcn[rr];
            int i = 0;
            for (; i + 2 <= cnt; i += 2){           // coalesced: lanes read 64 contiguous dwords
                unsigned u0 = ep[i * 64];
                unsigned u1 = ep[i * 64 + 64];
                uint4 q0 = T4[u0 & 0xFFFFu];
                uint4 q1 = T4[u1 & 0xFFFFu];
                float v0 = __uint_as_float(u0 & 0xFFFF0000u);
                float v1 = __uint_as_float(u1 & 0xFFFF0000u);
                a0 = fmaf(v0, BLO(q0.x), a0);  a1 = fmaf(v0, BHI(q0.x), a1);
                a2 = fmaf(v0, BLO(q0.y), a2);  a3 = fmaf(v0, BHI(q0.y), a3);
                a4 = fmaf(v0, BLO(q0.z), a4);  a5 = fmaf(v0, BHI(q0.z), a5);
                a6 = fmaf(v0, BLO(q0.w), a6);  a7 = fmaf(v0, BHI(q0.w), a7);
                a0 = fmaf(v1, BLO(q1.x), a0);  a1 = fmaf(v1, BHI(q1.x), a1);
                a2 = fmaf(v1, BLO(q1.y), a2);  a3 = fmaf(v1, BHI(q1.y), a3);
                a4 = fmaf(v1, BLO(q1.z), a4);  a5 = fmaf(v1, BHI(q1.z), a5);
                a6 = fmaf(v1, BLO(q1.w), a6);  a7 = fmaf(v1, BHI(q1.w), a7);
            }
            if (i < cnt){
                unsigned u0 = ep[i * 64];
                uint4 q0 = T4[u0 & 0xFFFFu];
                float v0 = __uint_as_float(u0 & 0xFFFF0000u);
                a0 = fmaf(v0, BLO(q0.x), a0);  a1 = fmaf(v0, BHI(q0.x), a1);
                a2 = fmaf(v0, BLO(q0.y), a2);  a3 = fmaf(v0, BHI(q0.y), a3);
                a4 = fmaf(v0, BLO(q0.z), a4);  a5 = fmaf(v0, BHI(q0.z), a5);
                a6 = fmaf(v0, BLO(q0.w), a6);  a7 = fmaf(v0, BHI(q0.w), a7);
            }
            if (k > 1){
                a0 = 2.f*a0 - BLO(tm2[rr].x);  a1 = 2.f*a1 - BHI(tm2[rr].x);
                a2 = 2.f*a2 - BLO(tm2[rr].y);  a3 = 2.f*a3 - BHI(tm2[rr].y);
                a4 = 2.f*a4 - BLO(tm2[rr].z);  a5 = 2.f*a5 - BHI(tm2[rr].z);
                a6 = 2.f*a6 - BLO(tm2[rr].w);  a7 = 2.f*a7 - BHI(tm2[rr].w);
            }
            uint4 nq;
            nq.x = packbf(a0, a1); nq.y = packbf(a2, a3);
            nq.z = packbf(a4, a5); nq.w = packbf(a6, a7);
            nst[rr] = nq;
            basisT[(size_t)(stl * 1024 + (vr[rr] >> 2)) * 1024
                   + (((vr[rr] >> 1) & 1) << 9) + (k << 6) + bb_f + (vr[rr] & 1)] = nq;
        }
        #pragma unroll
        for (int rr = 0; rr < 4; ++rr) tm2[rr] = T4[vr[rr]];   // T_{k-1} own rows
        __syncthreads();
        #pragma unroll
        for (int rr = 0; rr < 4; ++rr) T4[vr[rr]] = nst[rr];   // LDS <- T_k
        __syncthreads();
    }
}

// ---------------- Phase B: projection GEMM (MFMA bf16), 128 rows/block ----------------
__global__ __launch_bounds__(256, 2) void k_phaseB(
    const uint4* __restrict__ basisT, const uint4* __restrict__ wtab,
    const float* __restrict__ bias, float* __restrict__ out, int st0)
{
    __shared__ uint4 AW[5120];   // A: 4096 uint4 (64 KB, 4 subtiles) + W: 1024 uint4 (16 KB)
    int t = threadIdx.x;
    int tile128 = blockIdx.x;
    const uint4* gA = basisT + (size_t)tile128 * 4096;

    #pragma unroll
    for (int it = 0; it < 16; ++it) AW[(it << 8) + t] = gA[(it << 8) + t];
    #pragma unroll
    for (int it = 0; it < 4; ++it)  AW[4096 + (it << 8) + t] = wtab[(it << 8) + t];
    __syncthreads();

    int lane = t & 63, w = t >> 6;
    unsigned ldsA = (unsigned)(size_t)(&AW[0]);
    unsigned abase = ldsA + w * 16384 + (lane << 3);
    const char* wbase = (const char*)&AW[4096];

    f32x4 acc00 = {0,0,0,0}, acc01 = {0,0,0,0}, acc10 = {0,0,0,0}, acc11 = {0,0,0,0};
    #pragma unroll
    for (int ki = 0; ki < 8; ++ki){
        s16x4 x0, x1, x2, x3;
        unsigned a0 = abase + (ki << 10);
        unsigned a1 = a0 + 8192;
        asm volatile("ds_read_b64_tr_b16 %0, %4\n\t"
                     "ds_read_b64_tr_b16 %1, %4 offset:512\n\t"
                     "ds_read_b64_tr_b16 %2, %5\n\t"
                     "ds_read_b64_tr_b16 %3, %5 offset:512\n\t"
                     "s_waitcnt lgkmcnt(0)"
                     : "=&v"(x0), "=&v"(x1), "=&v"(x2), "=&v"(x3)
                     : "v"(a0), "v"(a1));
        __builtin_amdgcn_sched_barrier(0);
        s16x8 af0, af1;
        af0[0]=x0[0]; af0[1]=x0[1]; af0[2]=x0[2]; af0[3]=x0[3];
        af0[4]=x1[0]; af0[5]=x1[1]; af0[6]=x1[2]; af0[7]=x1[3];
        af1[0]=x2[0]; af1[1]=x2[1]; af1[2]=x2[2]; af1[3]=x2[3];
        af1[4]=x3[0]; af1[5]=x3[1]; af1[6]=x3[2]; af1[7]=x3[3];
        s16x8 b0 = *(const s16x8*)(wbase + (((ki * 2 + 0) * 64 + lane) << 4));
        s16x8 b1 = *(const s16x8*)(wbase + (((ki * 2 + 1) * 64 + lane) << 4));
        acc00 = __builtin_amdgcn_mfma_f32_16x16x32_bf16(af0, b0, acc00, 0, 0, 0);
        acc01 = __builtin_amdgcn_mfma_f32_16x16x32_bf16(af0, b1, acc01, 0, 0, 0);
        acc10 = __builtin_amdgcn_mfma_f32_16x16x32_bf16(af1, b0, acc10, 0, 0, 0);
        acc11 = __builtin_amdgcn_mfma_f32_16x16x32_bf16(af1, b1, acc11, 0, 0, 0);
    }

    // rows: r_local = tile128*128 + w*32 + msub*16 + (lane>>4)*4 + j ; fo = nh*16 + (lane&15)
    int rbase = tile128 * 128 + w * 32 + ((lane >> 4) << 2) + st0 * 32768;
    #pragma unroll
    for (int msub = 0; msub < 2; ++msub){
        #pragma unroll
        for (int nh = 0; nh < 2; ++nh){
            f32x4 acc = (msub == 0) ? (nh == 0 ? acc00 : acc01)
                                    : (nh == 0 ? acc10 : acc11);
            int r  = rbase + msub * 16;
            int st = r >> 15, rem = r & 32767;
            int v  = rem >> 3, sl0 = rem & 7;
            int fo = nh * 16 + (lane & 15);
            float bs = bias[fo];
            float4 o; o.x = acc[0]+bs; o.y = acc[1]+bs; o.z = acc[2]+bs; o.w = acc[3]+bs;
            *(float4*)(out + ((size_t)fo * V_N + v) * S_N + st * 8 + sl0) = o;
        }
    }
}

// ---------------- host ----------------
extern "C" void kernel_launch(void* const* d_in, const int* in_sizes, int n_in,
                              void* d_out, int out_size, void* d_ws, size_t ws_size,
                              hipStream_t stream)
{
    const float* inp  = (const float*)d_in[0];
    const float* wgt  = (const float*)d_in[1];
    const float* bias = (const float*)d_in[2];
    const float* vals = (const float*)d_in[3];
    const int*   rows = (const int*)d_in[4];
    const int*   cols = (const int*)d_in[5];
    float* out = (float*)d_out;

    char* ws = (char*)d_ws;
    size_t o = 0;
    auto alloc = [&](size_t bytes) -> void* {
        void* p = ws + o; o = (o + bytes + 255) & ~(size_t)255; return p;
    };
    int* counts    = (int*)alloc(4096 * 4);
    int* dh        = (int*)alloc(64 * 4);
    int* dhoff     = (int*)alloc(64 * 4);
    int* row_order = (int*)alloc(4096 * 4);
    int* sp        = (int*)alloc(4096 * 4);
    int* counts2   = (int*)alloc(4096 * 4);
    int* gcnt      = (int*)alloc(64 * 4);
    int* goff      = (int*)alloc(64 * 4);
    int* rcur      = (int*)alloc(4096 * 4);
    unsigned* ell  = (unsigned*)alloc(1048576);      // 64*64*64*4 B hard cap
    uint4* wtab    = (uint4*)alloc(8192 * 2);
    size_t used = o;

    size_t per_st = (size_t)1024 * 1024 * 16;        // 16.78 MB per s8-tile
    size_t avail = (ws_size > used) ? (ws_size - used) : 0;
    int tiles_c = (int)(avail / per_st);
    if (tiles_c > ST_TOT) tiles_c = ST_TOT;
    if (tiles_c < 1) tiles_c = 1;
    uint4* basisT = (uint4*)alloc(per_st * tiles_c);

    hipMemsetAsync(counts, 0, 4096 * 4, stream);
    hipMemsetAsync(dh, 0, 64 * 4, stream);
    hipMemsetAsync(rcur, 0, 4096 * 4, stream);
    hipMemsetAsync(ell, 0, 1048576, stream);
    k_hist    <<<144, 256, 0, stream>>>(rows, counts);
    k_deghist <<<16, 256, 0, stream>>>(counts, dh);
    k_degscan <<<1, 64, 0, stream>>>(dh, dhoff);
    k_sortrows<<<16, 256, 0, stream>>>(counts, dhoff, row_order, sp, counts2);
    k_goff    <<<1, 64, 0, stream>>>(counts2, gcnt, goff);
    k_fillell <<<144, 256, 0, stream>>>(rows, cols, vals, sp, gcnt, goff, rcur, ell);
    k_wtab    <<<32, 256, 0, stream>>>(wgt, (unsigned short*)wtab);

    for (int st0 = 0; st0 < ST_TOT; st0 += tiles_c){
        int tc = ST_TOT - st0; if (tc > tiles_c) tc = tiles_c;
        k_phaseA<<<32 * tc, 1024, 0, stream>>>(inp, row_order, goff, gcnt, ell, basisT, st0);
        k_phaseB<<<tc * 256, 256, 0, stream>>>(basisT, wtab, bias, out, st0);
    }
}

// Round 3
// 687.866 us; speedup vs baseline: 2.2311x; 1.2019x over previous
//
#include <hip/hip_runtime.h>
#include <stdint.h>

#define V_N    4096
#define NNZ_N  36864
#define S_N    216        // X*Y*Z = 6*6*6
#define ST_TOT 27         // S_N / 8
#define PLANES 256        // K * FIN

typedef float  f32x4 __attribute__((ext_vector_type(4)));
typedef short  s16x4 __attribute__((ext_vector_type(4)));
typedef short  s16x8 __attribute__((ext_vector_type(8)));

static __device__ __forceinline__ unsigned short f2bf(float f){
    union { float f; unsigned u; } x; x.f = f;
    unsigned r = x.u + 0x7FFFu + ((x.u >> 16) & 1u);   // round-to-nearest-even
    return (unsigned short)(r >> 16);
}
static __device__ __forceinline__ unsigned packbf(float lo, float hi){
    return (unsigned)f2bf(lo) | ((unsigned)f2bf(hi) << 16);
}
#define BLO(u) __uint_as_float((u) << 16)
#define BHI(u) __uint_as_float((u) & 0xFFFF0000u)

// ---------------- graph prep ----------------
__global__ void k_hist(const int* __restrict__ rows, int* __restrict__ counts){
    int e = blockIdx.x * 256 + threadIdx.x;
    if (e < NNZ_N) atomicAdd(&counts[rows[e]], 1);
}
__global__ void k_deghist(const int* __restrict__ counts, int* __restrict__ dh){
    int v = blockIdx.x * 256 + threadIdx.x;
    if (v < V_N){ int d = counts[v]; if (d > 63) d = 63; atomicAdd(&dh[d], 1); }
}
__global__ void k_degscan(const int* __restrict__ dh, int* __restrict__ dhoff){
    if (threadIdx.x == 0){ int s = 0; for (int i = 0; i < 64; ++i){ dhoff[i] = s; s += dh[i]; } }
}
__global__ void k_sortrows(const int* __restrict__ counts, int* __restrict__ dhoff,
                           int* __restrict__ row_order, int* __restrict__ sp,
                           int* __restrict__ counts2){
    int v = blockIdx.x * 256 + threadIdx.x;
    if (v < V_N){
        int d = counts[v]; int db = d > 63 ? 63 : d;
        int pos = atomicAdd(&dhoff[db], 1);
        row_order[pos] = v; sp[v] = pos; counts2[pos] = d;
    }
}
// 64 groups of 64 sorted rows; slots/row = group max (clamped 64) + 3 pad rows (zeros)
__global__ void k_goff(const int* __restrict__ counts2, int* __restrict__ gcnt,
                       int* __restrict__ goff){
    if (threadIdx.x == 0){
        int off = 0;
        for (int g = 0; g < 64; ++g){
            int d = counts2[g * 64 + 63];
            if (d > 64) d = 64;
            gcnt[g] = d; goff[g] = off; off += (d + 3) * 64;
        }
    }
}
// lane-transposed zero-padded ELL: slot(g, i, lane) = goff[g] + i*64 + lane
// entry = (col*16) | (bf16(val) << 16)   -- low16 is the T4 byte offset
__global__ void k_fillell(const int* __restrict__ rows, const int* __restrict__ cols,
                          const float* __restrict__ vals, const int* __restrict__ sp,
                          const int* __restrict__ gcnt, const int* __restrict__ goff,
                          int* __restrict__ rcur, unsigned* __restrict__ ell){
    int e = blockIdx.x * 256 + threadIdx.x;
    if (e < NNZ_N){
        int r = rows[e]; int s = sp[r]; int g = s >> 6; int l = s & 63;
        int i = atomicAdd(&rcur[r], 1);
        if (i < gcnt[g])
            ell[goff[g] + i * 64 + l] =
                ((unsigned)cols[e] << 4) | ((unsigned)f2bf(vals[e]) << 16);
    }
}
// W packed into MFMA B-fragment order
__global__ void k_wtab(const float* __restrict__ w, unsigned short* __restrict__ wtab){
    int idx = blockIdx.x * 256 + threadIdx.x;   // 0..8191
    int slot = idx >> 3, j = idx & 7;
    int ki = slot >> 7, nh = (slot >> 6) & 1, l = slot & 63;
    int p  = ki * 32 + ((l >> 4) << 3) + j;
    int fo = nh * 16 + (l & 15);
    wtab[idx] = f2bf(w[p * 32 + fo]);
}

// ---------------- Phase A: LDS-resident Chebyshev recurrence ----------------
// basis layout: basis[(stl*256 + p)*4096 + v]  (uint4 = 8 sl bf16) -- fully coalesced writes
__global__ __launch_bounds__(1024, 8) void k_phaseA(
    const float* __restrict__ in, const int* __restrict__ row_order,
    const int* __restrict__ goff, const int* __restrict__ gcnt,
    const unsigned* __restrict__ ell, uint4* __restrict__ basis, int st0)
{
    __shared__ uint4 T4[V_N];        // 64 KB
    int f   = blockIdx.x & 31;
    int stl = blockIdx.x >> 5;
    int st_g = st0 + stl;
    int t = threadIdx.x;

    // T0: strided global read -> LDS + basis plane p=f (coalesced store)
    size_t pb0 = ((size_t)(stl * 256 + f)) << 12;
    #pragma unroll
    for (int rr = 0; rr < 4; ++rr){
        int v = t + rr * 1024;
        const float* src = in + ((size_t)f * V_N + v) * S_N + st_g * 8;
        float4 a = ((const float4*)src)[0];
        float4 b = ((const float4*)src)[1];
        uint4 q;
        q.x = packbf(a.x, a.y); q.y = packbf(a.z, a.w);
        q.z = packbf(b.x, b.y); q.w = packbf(b.z, b.w);
        T4[v] = q;
        basis[pb0 + v] = q;
    }
    __syncthreads();

    // wave w owns groups {w, w+16, w+32, w+48}  (strided => balanced degrees)
    int w = t >> 6, lane = t & 63;
    int vr[4], gba[4], gcn[4];
    #pragma unroll
    for (int rr = 0; rr < 4; ++rr){
        int g = w + rr * 16;
        vr[rr]  = row_order[g * 64 + lane];
        gba[rr] = goff[g] + lane;
        gcn[rr] = __builtin_amdgcn_readfirstlane(gcnt[g]);
    }
    uint4 tm2[4];
    #pragma unroll
    for (int rr = 0; rr < 4; ++rr) tm2[rr] = T4[vr[rr]];   // T0 own rows

    for (int k = 1; k < 8; ++k){
        uint4 nst[4];
        #pragma unroll
        for (int rr = 0; rr < 4; ++rr){
            float a0=0,a1=0,a2=0,a3=0,a4=0,a5=0,a6=0,a7=0;
            const unsigned* ep = ell + gba[rr];
            int cnt = gcn[rr];
            unsigned u0 = ep[0];
            unsigned u1 = ep[64];
            for (int i = 0; i < cnt; i += 2){
                unsigned n0 = ep[(i + 2) << 6];     // prefetch next pair (pad rows are 0)
                unsigned n1 = ep[(i + 3) << 6];
                uint4 q0 = *(const uint4*)((const char*)T4 + (u0 & 0xFFF0u));
                uint4 q1 = *(const uint4*)((const char*)T4 + (u1 & 0xFFF0u));
                float v0 = __uint_as_float(u0 & 0xFFFF0000u);
                float v1 = __uint_as_float(u1 & 0xFFFF0000u);
                a0 = fmaf(v0, BLO(q0.x), a0);  a1 = fmaf(v0, BHI(q0.x), a1);
                a2 = fmaf(v0, BLO(q0.y), a2);  a3 = fmaf(v0, BHI(q0.y), a3);
                a4 = fmaf(v0, BLO(q0.z), a4);  a5 = fmaf(v0, BHI(q0.z), a5);
                a6 = fmaf(v0, BLO(q0.w), a6);  a7 = fmaf(v0, BHI(q0.w), a7);
                a0 = fmaf(v1, BLO(q1.x), a0);  a1 = fmaf(v1, BHI(q1.x), a1);
                a2 = fmaf(v1, BLO(q1.y), a2);  a3 = fmaf(v1, BHI(q1.y), a3);
                a4 = fmaf(v1, BLO(q1.z), a4);  a5 = fmaf(v1, BHI(q1.z), a5);
                a6 = fmaf(v1, BLO(q1.w), a6);  a7 = fmaf(v1, BHI(q1.w), a7);
                u0 = n0; u1 = n1;
            }
            if (k > 1){
                a0 = fmaf(2.f, a0, -BLO(tm2[rr].x));  a1 = fmaf(2.f, a1, -BHI(tm2[rr].x));
                a2 = fmaf(2.f, a2, -BLO(tm2[rr].y));  a3 = fmaf(2.f, a3, -BHI(tm2[rr].y));
                a4 = fmaf(2.f, a4, -BLO(tm2[rr].z));  a5 = fmaf(2.f, a5, -BHI(tm2[rr].z));
                a6 = fmaf(2.f, a6, -BLO(tm2[rr].w));  a7 = fmaf(2.f, a7, -BHI(tm2[rr].w));
            }
            nst[rr].x = packbf(a0, a1); nst[rr].y = packbf(a2, a3);
            nst[rr].z = packbf(a4, a5); nst[rr].w = packbf(a6, a7);
        }
        #pragma unroll
        for (int rr = 0; rr < 4; ++rr) tm2[rr] = T4[vr[rr]];   // T_{k-1} own rows
        __syncthreads();
        #pragma unroll
        for (int rr = 0; rr < 4; ++rr) T4[vr[rr]] = nst[rr];   // LDS <- T_k
        __syncthreads();
        // coalesced basis write of T_k from LDS (natural row order)
        size_t pb = ((size_t)(stl * 256 + k * 32 + f)) << 12;
        #pragma unroll
        for (int rr = 0; rr < 4; ++rr){
            int v = t + rr * 1024;
            basis[pb + v] = T4[v];
        }
    }
}

// ---------------- Phase B: projection GEMM (MFMA bf16), 128 rows/block ----------------
__global__ __launch_bounds__(256, 2) void k_phaseB(
    const uint4* __restrict__ basis, const uint4* __restrict__ wtab,
    const float* __restrict__ bias, float* __restrict__ out, int st0)
{
    __shared__ uint4 AW[5120];   // A: 4096 uint4 (64 KB) + W: 1024 uint4 (16 KB)
    int t = threadIdx.x;
    int tile = blockIdx.x;            // chunk-local: stl = tile>>8, vblk = tile&255
    int stl = tile >> 8, vblk = tile & 255;
    const uint4* gA = basis + ((size_t)stl << 20) + (vblk << 4);

    // coalesced global read (16 lanes x 16B per plane) + permuted ds_write for tr_b16
    #pragma unroll
    for (int it = 0; it < 16; ++it){
        int g = (it << 8) + t;
        int p = g >> 4, vrr = g & 15;
        uint4 q = gA[((size_t)p << 12) + vrr];
        int b = ((vrr >> 2) << 10) + (((vrr >> 1) & 1) << 9)
              + ((p >> 5) << 6) + (((p >> 2) & 1) << 5) + (((p >> 3) & 3) << 3)
              + ((p & 3) << 1) + (vrr & 1);
        AW[b] = q;
    }
    #pragma unroll
    for (int it = 0; it < 4; ++it)  AW[4096 + (it << 8) + t] = wtab[(it << 8) + t];
    __syncthreads();

    int lane = t & 63, w = t >> 6;
    unsigned ldsA = (unsigned)(size_t)(&AW[0]);
    unsigned abase = ldsA + w * 16384 + (lane << 3);
    const char* wbase = (const char*)&AW[4096];

    f32x4 acc00 = {0,0,0,0}, acc01 = {0,0,0,0}, acc10 = {0,0,0,0}, acc11 = {0,0,0,0};
    #pragma unroll
    for (int ki = 0; ki < 8; ++ki){
        s16x4 x0, x1, x2, x3;
        unsigned a0 = abase + (ki << 10);
        unsigned a1 = a0 + 8192;
        asm volatile("ds_read_b64_tr_b16 %0, %4\n\t"
                     "ds_read_b64_tr_b16 %1, %4 offset:512\n\t"
                     "ds_read_b64_tr_b16 %2, %5\n\t"
                     "ds_read_b64_tr_b16 %3, %5 offset:512\n\t"
                     "s_waitcnt lgkmcnt(0)"
                     : "=&v"(x0), "=&v"(x1), "=&v"(x2), "=&v"(x3)
                     : "v"(a0), "v"(a1));
        __builtin_amdgcn_sched_barrier(0);
        s16x8 af0, af1;
        af0[0]=x0[0]; af0[1]=x0[1]; af0[2]=x0[2]; af0[3]=x0[3];
        af0[4]=x1[0]; af0[5]=x1[1]; af0[6]=x1[2]; af0[7]=x1[3];
        af1[0]=x2[0]; af1[1]=x2[1]; af1[2]=x2[2]; af1[3]=x2[3];
        af1[4]=x3[0]; af1[5]=x3[1]; af1[6]=x3[2]; af1[7]=x3[3];
        s16x8 b0 = *(const s16x8*)(wbase + (((ki * 2 + 0) * 64 + lane) << 4));
        s16x8 b1 = *(const s16x8*)(wbase + (((ki * 2 + 1) * 64 + lane) << 4));
        acc00 = __builtin_amdgcn_mfma_f32_16x16x32_bf16(af0, b0, acc00, 0, 0, 0);
        acc01 = __builtin_amdgcn_mfma_f32_16x16x32_bf16(af0, b1, acc01, 0, 0, 0);
        acc10 = __builtin_amdgcn_mfma_f32_16x16x32_bf16(af1, b0, acc10, 0, 0, 0);
        acc11 = __builtin_amdgcn_mfma_f32_16x16x32_bf16(af1, b1, acc11, 0, 0, 0);
    }

    #pragma unroll
    for (int msub = 0; msub < 2; ++msub){
        #pragma unroll
        for (int nh = 0; nh < 2; ++nh){
            f32x4 acc = (msub == 0) ? (nh == 0 ? acc00 : acc01)
                                    : (nh == 0 ? acc10 : acc11);
            int r  = tile * 128 + w * 32 + msub * 16 + ((lane >> 4) << 2);
            int st = st0 + (r >> 15), rem = r & 32767;
            int v  = rem >> 3, sl0 = rem & 7;
            int fo = nh * 16 + (lane & 15);
            float bs = bias[fo];
            float4 o; o.x = acc[0]+bs; o.y = acc[1]+bs; o.z = acc[2]+bs; o.w = acc[3]+bs;
            *(float4*)(out + ((size_t)fo * V_N + v) * S_N + st * 8 + sl0) = o;
        }
    }
}

// ---------------- host ----------------
extern "C" void kernel_launch(void* const* d_in, const int* in_sizes, int n_in,
                              void* d_out, int out_size, void* d_ws, size_t ws_size,
                              hipStream_t stream)
{
    const float* inp  = (const float*)d_in[0];
    const float* wgt  = (const float*)d_in[1];
    const float* bias = (const float*)d_in[2];
    const float* vals = (const float*)d_in[3];
    const int*   rows = (const int*)d_in[4];
    const int*   cols = (const int*)d_in[5];
    float* out = (float*)d_out;

    char* ws = (char*)d_ws;
    size_t o = 0;
    auto alloc = [&](size_t bytes) -> void* {
        void* p = ws + o; o = (o + bytes + 255) & ~(size_t)255; return p;
    };
    const size_t ELL_B = (size_t)64 * 67 * 64 * 4;   // 1.05 MB hard cap
    int* counts    = (int*)alloc(4096 * 4);
    int* dh        = (int*)alloc(64 * 4);
    int* dhoff     = (int*)alloc(64 * 4);
    int* row_order = (int*)alloc(4096 * 4);
    int* sp        = (int*)alloc(4096 * 4);
    int* counts2   = (int*)alloc(4096 * 4);
    int* gcnt      = (int*)alloc(64 * 4);
    int* goff      = (int*)alloc(64 * 4);
    int* rcur      = (int*)alloc(4096 * 4);
    unsigned* ell  = (unsigned*)alloc(ELL_B);
    uint4* wtab    = (uint4*)alloc(8192 * 2);
    size_t used = o;

    size_t per_st = (size_t)PLANES * V_N * 16;       // 16.78 MB per s8-tile
    size_t avail = (ws_size > used) ? (ws_size - used) : 0;
    int tiles_c = (int)(avail / per_st);
    if (tiles_c > ST_TOT) tiles_c = ST_TOT;
    if (tiles_c < 1) tiles_c = 1;
    uint4* basis = (uint4*)alloc(per_st * tiles_c);

    hipMemsetAsync(counts, 0, 4096 * 4, stream);
    hipMemsetAsync(dh, 0, 64 * 4, stream);
    hipMemsetAsync(rcur, 0, 4096 * 4, stream);
    hipMemsetAsync(ell, 0, ELL_B, stream);
    k_hist    <<<144, 256, 0, stream>>>(rows, counts);
    k_deghist <<<16, 256, 0, stream>>>(counts, dh);
    k_degscan <<<1, 64, 0, stream>>>(dh, dhoff);
    k_sortrows<<<16, 256, 0, stream>>>(counts, dhoff, row_order, sp, counts2);
    k_goff    <<<1, 64, 0, stream>>>(counts2, gcnt, goff);
    k_fillell <<<144, 256, 0, stream>>>(rows, cols, vals, sp, gcnt, goff, rcur, ell);
    k_wtab    <<<32, 256, 0, stream>>>(wgt, (unsigned short*)wtab);

    for (int st0 = 0; st0 < ST_TOT; st0 += tiles_c){
        int tc = ST_TOT - st0; if (tc > tiles_c) tc = tiles_c;
        k_phaseA<<<32 * tc, 1024, 0, stream>>>(inp, row_order, goff, gcnt, ell, basis, st0);
        k_phaseB<<<tc * 256, 256, 0, stream>>>(basis, wtab, bias, out, st0);
    }
}

// Round 4
// 678.575 us; speedup vs baseline: 2.2617x; 1.0137x over previous
//
#include <hip/hip_runtime.h>
#include <stdint.h>

#define V_N    4096
#define NNZ_N  36864
#define S_N    216        // X*Y*Z = 6*6*6
#define ST_TOT 27         // S_N / 8
#define PLANES 256        // K * FIN

typedef float  f32x4 __attribute__((ext_vector_type(4)));
typedef short  s16x4 __attribute__((ext_vector_type(4)));
typedef short  s16x8 __attribute__((ext_vector_type(8)));

static __device__ __forceinline__ unsigned short f2bf(float f){
    union { float f; unsigned u; } x; x.f = f;
    unsigned r = x.u + 0x7FFFu + ((x.u >> 16) & 1u);   // round-to-nearest-even
    return (unsigned short)(r >> 16);
}
static __device__ __forceinline__ unsigned packbf(float lo, float hi){
    return (unsigned)f2bf(lo) | ((unsigned)f2bf(hi) << 16);
}
#define BLO(u) __uint_as_float((u) << 16)
#define BHI(u) __uint_as_float((u) & 0xFFFF0000u)

// ---------------- graph prep ----------------
__global__ void k_hist(const int* __restrict__ rows, int* __restrict__ counts){
    int e = blockIdx.x * 256 + threadIdx.x;
    if (e < NNZ_N) atomicAdd(&counts[rows[e]], 1);
}
__global__ void k_deghist(const int* __restrict__ counts, int* __restrict__ dh){
    int v = blockIdx.x * 256 + threadIdx.x;
    if (v < V_N){ int d = counts[v]; if (d > 63) d = 63; atomicAdd(&dh[d], 1); }
}
__global__ void k_degscan(const int* __restrict__ dh, int* __restrict__ dhoff){
    if (threadIdx.x == 0){ int s = 0; for (int i = 0; i < 64; ++i){ dhoff[i] = s; s += dh[i]; } }
}
__global__ void k_sortrows(const int* __restrict__ counts, int* __restrict__ dhoff,
                           int* __restrict__ row_order, int* __restrict__ sp,
                           int* __restrict__ counts2){
    int v = blockIdx.x * 256 + threadIdx.x;
    if (v < V_N){
        int d = counts[v]; int db = d > 63 ? 63 : d;
        int pos = atomicAdd(&dhoff[db], 1);
        row_order[pos] = v; sp[v] = pos; counts2[pos] = d;
    }
}
// 64 groups of 64 sorted rows; slots/row = group max (clamped 64) + 3 pad rows (zeros)
__global__ void k_goff(const int* __restrict__ counts2, int* __restrict__ gcnt,
                       int* __restrict__ goff){
    if (threadIdx.x == 0){
        int off = 0;
        for (int g = 0; g < 64; ++g){
            int d = counts2[g * 64 + 63];
            if (d > 64) d = 64;
            gcnt[g] = d; goff[g] = off; off += (d + 3) * 64;
        }
    }
}
// lane-transposed zero-padded ELL: slot(g, i, lane) = goff[g] + i*64 + lane
// entry = (col*16) | (bf16(val) << 16)   -- low16 is the T4 byte offset
__global__ void k_fillell(const int* __restrict__ rows, const int* __restrict__ cols,
                          const float* __restrict__ vals, const int* __restrict__ sp,
                          const int* __restrict__ gcnt, const int* __restrict__ goff,
                          int* __restrict__ rcur, unsigned* __restrict__ ell){
    int e = blockIdx.x * 256 + threadIdx.x;
    if (e < NNZ_N){
        int r = rows[e]; int s = sp[r]; int g = s >> 6; int l = s & 63;
        int i = atomicAdd(&rcur[r], 1);
        if (i < gcnt[g])
            ell[goff[g] + i * 64 + l] =
                ((unsigned)cols[e] << 4) | ((unsigned)f2bf(vals[e]) << 16);
    }
}
// W packed into MFMA B-fragment order
__global__ void k_wtab(const float* __restrict__ w, unsigned short* __restrict__ wtab){
    int idx = blockIdx.x * 256 + threadIdx.x;   // 0..8191
    int slot = idx >> 3, j = idx & 7;
    int ki = slot >> 7, nh = (slot >> 6) & 1, l = slot & 63;
    int p  = ki * 32 + ((l >> 4) << 3) + j;
    int fo = nh * 16 + (l & 15);
    wtab[idx] = f2bf(w[p * 32 + fo]);
}

// ---------------- k_pre: input transpose -> k=0 basis planes (bf16) ----------------
// block = (f, vblk of 64 v). Reads 64x216 f32 contiguous, writes tc planes coalesced.
__global__ __launch_bounds__(256, 4) void k_pre(
    const float* __restrict__ in, uint4* __restrict__ basis, int st0, int tc)
{
    __shared__ unsigned short lds[64 * 218];   // 27.3 KB, row stride 436 B
    int bid = blockIdx.x;
    int f = bid >> 6, vblk = bid & 63;
    int t = threadIdx.x;
    const float* src = in + ((size_t)f * V_N + vblk * 64) * S_N;

    #pragma unroll
    for (int it = 0; it < 14; ++it){
        int idx = t + it * 256;                 // float4 index, 0..3455
        if (idx < 3456){
            int vloc = (int)(((unsigned)idx * 4855u) >> 18);   // idx / 54
            int s4   = idx - vloc * 54;
            float4 a = ((const float4*)src)[idx];
            uint2 q; q.x = packbf(a.x, a.y); q.y = packbf(a.z, a.w);
            *(uint2*)((char*)lds + vloc * 436 + s4 * 8) = q;
        }
    }
    __syncthreads();
    #pragma unroll
    for (int it = 0; it < 7; ++it){
        int idx = t + it * 256;
        if (idx < tc * 64){
            int stl = idx >> 6, vl = idx & 63;
            uint4 q = *(const uint4*)((const char*)lds + vl * 436 + (st0 + stl) * 16);
            basis[(((size_t)(stl * 256 + f)) << 12) + vblk * 64 + vl] = q;
        }
    }
}

// ---------------- Phase A: LDS-resident Chebyshev recurrence ----------------
// basis layout: basis[(stl*256 + p)*4096 + v]  (uint4 = 8 sl bf16) -- coalesced
__global__ __launch_bounds__(1024, 8) void k_phaseA(
    const int* __restrict__ row_order,
    const int* __restrict__ goff, const int* __restrict__ gcnt,
    const unsigned* __restrict__ ell, uint4* __restrict__ basis, int st0)
{
    __shared__ uint4 T4[V_N];        // 64 KB
    int f   = blockIdx.x & 31;
    int stl = blockIdx.x >> 5;
    int t = threadIdx.x;

    // T0 from k_pre's plane (coalesced 64 KB read)
    const uint4* t0p = basis + (((size_t)(stl * 256 + f)) << 12);
    #pragma unroll
    for (int rr = 0; rr < 4; ++rr){
        int v = t + rr * 1024;
        T4[v] = t0p[v];
    }
    __syncthreads();

    // wave w owns groups {w, w+16, w+32, w+48}  (strided => balanced degrees)
    int w = t >> 6, lane = t & 63;
    int vr[4], gba[4], gcn[4];
    #pragma unroll
    for (int rr = 0; rr < 4; ++rr){
        int g = w + rr * 16;
        vr[rr]  = row_order[g * 64 + lane];
        gba[rr] = goff[g] + lane;
        gcn[rr] = __builtin_amdgcn_readfirstlane(gcnt[g]);
    }
    uint4 tm2[4];
    #pragma unroll
    for (int rr = 0; rr < 4; ++rr) tm2[rr] = T4[vr[rr]];   // T0 own rows

    for (int k = 1; k < 8; ++k){
        uint4 nst[4];
        #pragma unroll
        for (int rr = 0; rr < 4; ++rr){
            float a0=0,a1=0,a2=0,a3=0,a4=0,a5=0,a6=0,a7=0;
            const unsigned* ep = ell + gba[rr];
            int cnt = gcn[rr];
            unsigned u0 = ep[0];
            unsigned u1 = ep[64];
            for (int i = 0; i < cnt; i += 2){
                unsigned n0 = ep[(i + 2) << 6];     // prefetch next pair (pad rows are 0)
                unsigned n1 = ep[(i + 3) << 6];
                uint4 q0 = *(const uint4*)((const char*)T4 + (u0 & 0xFFF0u));
                uint4 q1 = *(const uint4*)((const char*)T4 + (u1 & 0xFFF0u));
                float v0 = __uint_as_float(u0 & 0xFFFF0000u);
                float v1 = __uint_as_float(u1 & 0xFFFF0000u);
                a0 = fmaf(v0, BLO(q0.x), a0);  a1 = fmaf(v0, BHI(q0.x), a1);
                a2 = fmaf(v0, BLO(q0.y), a2);  a3 = fmaf(v0, BHI(q0.y), a3);
                a4 = fmaf(v0, BLO(q0.z), a4);  a5 = fmaf(v0, BHI(q0.z), a5);
                a6 = fmaf(v0, BLO(q0.w), a6);  a7 = fmaf(v0, BHI(q0.w), a7);
                a0 = fmaf(v1, BLO(q1.x), a0);  a1 = fmaf(v1, BHI(q1.x), a1);
                a2 = fmaf(v1, BLO(q1.y), a2);  a3 = fmaf(v1, BHI(q1.y), a3);
                a4 = fmaf(v1, BLO(q1.z), a4);  a5 = fmaf(v1, BHI(q1.z), a5);
                a6 = fmaf(v1, BLO(q1.w), a6);  a7 = fmaf(v1, BHI(q1.w), a7);
                u0 = n0; u1 = n1;
            }
            if (k > 1){
                a0 = fmaf(2.f, a0, -BLO(tm2[rr].x));  a1 = fmaf(2.f, a1, -BHI(tm2[rr].x));
                a2 = fmaf(2.f, a2, -BLO(tm2[rr].y));  a3 = fmaf(2.f, a3, -BHI(tm2[rr].y));
                a4 = fmaf(2.f, a4, -BLO(tm2[rr].z));  a5 = fmaf(2.f, a5, -BHI(tm2[rr].z));
                a6 = fmaf(2.f, a6, -BLO(tm2[rr].w));  a7 = fmaf(2.f, a7, -BHI(tm2[rr].w));
            }
            nst[rr].x = packbf(a0, a1); nst[rr].y = packbf(a2, a3);
            nst[rr].z = packbf(a4, a5); nst[rr].w = packbf(a6, a7);
        }
        #pragma unroll
        for (int rr = 0; rr < 4; ++rr) tm2[rr] = T4[vr[rr]];   // T_{k-1} own rows
        __syncthreads();
        #pragma unroll
        for (int rr = 0; rr < 4; ++rr) T4[vr[rr]] = nst[rr];   // LDS <- T_k
        __syncthreads();
        // coalesced basis write of T_k from LDS (natural row order)
        size_t pb = ((size_t)(stl * 256 + k * 32 + f)) << 12;
        #pragma unroll
        for (int rr = 0; rr < 4; ++rr){
            int v = t + rr * 1024;
            basis[pb + v] = T4[v];
        }
    }
}

// ---------------- Phase B: projection GEMM (MFMA bf16), 128 rows/block ----------------
__global__ __launch_bounds__(256, 2) void k_phaseB(
    const uint4* __restrict__ basis, const uint4* __restrict__ wtab,
    const float* __restrict__ bias, float* __restrict__ out, int st0)
{
    __shared__ uint4 AW[5120];   // A: 4096 uint4 (64 KB) + W: 1024 uint4 (16 KB)
    int t = threadIdx.x;
    int tile = blockIdx.x;            // chunk-local: stl = tile>>8, vblk = tile&255
    int stl = tile >> 8, vblk = tile & 255;
    const uint4* gA = basis + ((size_t)stl << 20) + (vblk << 4);

    // coalesced global read (16 lanes x 16B per plane) + permuted ds_write for tr_b16
    #pragma unroll
    for (int it = 0; it < 16; ++it){
        int g = (it << 8) + t;
        int p = g >> 4, vrr = g & 15;
        uint4 q = gA[((size_t)p << 12) + vrr];
        int b = ((vrr >> 2) << 10) + (((vrr >> 1) & 1) << 9)
              + ((p >> 5) << 6) + (((p >> 2) & 1) << 5) + (((p >> 3) & 3) << 3)
              + ((p & 3) << 1) + (vrr & 1);
        AW[b] = q;
    }
    #pragma unroll
    for (int it = 0; it < 4; ++it)  AW[4096 + (it << 8) + t] = wtab[(it << 8) + t];
    __syncthreads();

    int lane = t & 63, w = t >> 6;
    unsigned ldsA = (unsigned)(size_t)(&AW[0]);
    unsigned abase = ldsA + w * 16384 + (lane << 3);
    const char* wbase = (const char*)&AW[4096];

    f32x4 acc00 = {0,0,0,0}, acc01 = {0,0,0,0}, acc10 = {0,0,0,0}, acc11 = {0,0,0,0};
    #pragma unroll
    for (int ki = 0; ki < 8; ++ki){
        s16x4 x0, x1, x2, x3;
        unsigned a0 = abase + (ki << 10);
        unsigned a1 = a0 + 8192;
        asm volatile("ds_read_b64_tr_b16 %0, %4\n\t"
                     "ds_read_b64_tr_b16 %1, %4 offset:512\n\t"
                     "ds_read_b64_tr_b16 %2, %5\n\t"
                     "ds_read_b64_tr_b16 %3, %5 offset:512\n\t"
                     "s_waitcnt lgkmcnt(0)"
                     : "=&v"(x0), "=&v"(x1), "=&v"(x2), "=&v"(x3)
                     : "v"(a0), "v"(a1));
        __builtin_amdgcn_sched_barrier(0);
        s16x8 af0, af1;
        af0[0]=x0[0]; af0[1]=x0[1]; af0[2]=x0[2]; af0[3]=x0[3];
        af0[4]=x1[0]; af0[5]=x1[1]; af0[6]=x1[2]; af0[7]=x1[3];
        af1[0]=x2[0]; af1[1]=x2[1]; af1[2]=x2[2]; af1[3]=x2[3];
        af1[4]=x3[0]; af1[5]=x3[1]; af1[6]=x3[2]; af1[7]=x3[3];
        s16x8 b0 = *(const s16x8*)(wbase + (((ki * 2 + 0) * 64 + lane) << 4));
        s16x8 b1 = *(const s16x8*)(wbase + (((ki * 2 + 1) * 64 + lane) << 4));
        acc00 = __builtin_amdgcn_mfma_f32_16x16x32_bf16(af0, b0, acc00, 0, 0, 0);
        acc01 = __builtin_amdgcn_mfma_f32_16x16x32_bf16(af0, b1, acc01, 0, 0, 0);
        acc10 = __builtin_amdgcn_mfma_f32_16x16x32_bf16(af1, b0, acc10, 0, 0, 0);
        acc11 = __builtin_amdgcn_mfma_f32_16x16x32_bf16(af1, b1, acc11, 0, 0, 0);
    }

    // stage output tile in LDS (reuse A region), then fully-coalesced global store
    __syncthreads();
    float* outT = (float*)&AW[0];     // layout [fo][132] floats
    {
        int rl0 = w * 32 + ((lane >> 4) << 2);
        int foA = (lane & 15), foB = 16 + (lane & 15);
        float2 p;
        p.x = acc00[0]; p.y = acc00[1]; *(float2*)&outT[foA*132 + rl0]      = p;
        p.x = acc00[2]; p.y = acc00[3]; *(float2*)&outT[foA*132 + rl0 + 2]  = p;
        p.x = acc01[0]; p.y = acc01[1]; *(float2*)&outT[foB*132 + rl0]      = p;
        p.x = acc01[2]; p.y = acc01[3]; *(float2*)&outT[foB*132 + rl0 + 2]  = p;
        p.x = acc10[0]; p.y = acc10[1]; *(float2*)&outT[foA*132 + rl0 + 16] = p;
        p.x = acc10[2]; p.y = acc10[3]; *(float2*)&outT[foA*132 + rl0 + 18] = p;
        p.x = acc11[0]; p.y = acc11[1]; *(float2*)&outT[foB*132 + rl0 + 16] = p;
        p.x = acc11[2]; p.y = acc11[3]; *(float2*)&outT[foB*132 + rl0 + 18] = p;
    }
    __syncthreads();
    {
        int fo = t >> 3;
        float bs = bias[fo];
        float* gb = out + (size_t)fo * V_N * S_N;
        #pragma unroll
        for (int it = 0; it < 4; ++it){
            int rl = ((t & 7) << 2) + (it << 5);
            float2 p0 = *(const float2*)&outT[fo*132 + rl];
            float2 p1 = *(const float2*)&outT[fo*132 + rl + 2];
            int r = tile * 128 + rl;
            int st = st0 + (r >> 15), rem = r & 32767;
            int v = rem >> 3, sl = rem & 7;
            float4 o; o.x = p0.x + bs; o.y = p0.y + bs; o.z = p1.x + bs; o.w = p1.y + bs;
            *(float4*)(gb + (size_t)v * S_N + st * 8 + sl) = o;
        }
    }
}

// ---------------- host ----------------
extern "C" void kernel_launch(void* const* d_in, const int* in_sizes, int n_in,
                              void* d_out, int out_size, void* d_ws, size_t ws_size,
                              hipStream_t stream)
{
    const float* inp  = (const float*)d_in[0];
    const float* wgt  = (const float*)d_in[1];
    const float* bias = (const float*)d_in[2];
    const float* vals = (const float*)d_in[3];
    const int*   rows = (const int*)d_in[4];
    const int*   cols = (const int*)d_in[5];
    float* out = (float*)d_out;

    char* ws = (char*)d_ws;
    size_t o = 0;
    auto alloc = [&](size_t bytes) -> void* {
        void* p = ws + o; o = (o + bytes + 255) & ~(size_t)255; return p;
    };
    const size_t ELL_B = (size_t)64 * 67 * 64 * 4;   // 1.05 MB hard cap
    int* counts    = (int*)alloc(4096 * 4);
    int* dh        = (int*)alloc(64 * 4);
    int* dhoff     = (int*)alloc(64 * 4);
    int* row_order = (int*)alloc(4096 * 4);
    int* sp        = (int*)alloc(4096 * 4);
    int* counts2   = (int*)alloc(4096 * 4);
    int* gcnt      = (int*)alloc(64 * 4);
    int* goff      = (int*)alloc(64 * 4);
    int* rcur      = (int*)alloc(4096 * 4);
    unsigned* ell  = (unsigned*)alloc(ELL_B);
    uint4* wtab    = (uint4*)alloc(8192 * 2);
    size_t used = o;

    size_t per_st = (size_t)PLANES * V_N * 16;       // 16.78 MB per s8-tile
    size_t avail = (ws_size > used) ? (ws_size - used) : 0;
    int tiles_c = (int)(avail / per_st);
    if (tiles_c > ST_TOT) tiles_c = ST_TOT;
    if (tiles_c < 1) tiles_c = 1;
    uint4* basis = (uint4*)alloc(per_st * tiles_c);

    hipMemsetAsync(counts, 0, 4096 * 4, stream);
    hipMemsetAsync(dh, 0, 64 * 4, stream);
    hipMemsetAsync(rcur, 0, 4096 * 4, stream);
    hipMemsetAsync(ell, 0, ELL_B, stream);
    k_hist    <<<144, 256, 0, stream>>>(rows, counts);
    k_deghist <<<16, 256, 0, stream>>>(counts, dh);
    k_degscan <<<1, 64, 0, stream>>>(dh, dhoff);
    k_sortrows<<<16, 256, 0, stream>>>(counts, dhoff, row_order, sp, counts2);
    k_goff    <<<1, 64, 0, stream>>>(counts2, gcnt, goff);
    k_fillell <<<144, 256, 0, stream>>>(rows, cols, vals, sp, gcnt, goff, rcur, ell);
    k_wtab    <<<32, 256, 0, stream>>>(wgt, (unsigned short*)wtab);

    for (int st0 = 0; st0 < ST_TOT; st0 += tiles_c){
        int tc = ST_TOT - st0; if (tc > tiles_c) tc = tiles_c;
        k_pre   <<<2048, 256, 0, stream>>>(inp, basis, st0, tc);
        k_phaseA<<<32 * tc, 1024, 0, stream>>>(row_order, goff, gcnt, ell, basis, st0);
        k_phaseB<<<tc * 256, 256, 0, stream>>>(basis, wtab, bias, out, st0);
    }
}

// Round 6
// 525.259 us; speedup vs baseline: 2.9218x; 1.2919x over previous
//
#include <hip/hip_runtime.h>
#include <stdint.h>

#define V_N    4096
#define NNZ_N  36864
#define S_N    216        // X*Y*Z = 6*6*6
#define ST_TOT 27         // S_N / 8
#define PLANES 256        // K * FIN

typedef float  f32x2 __attribute__((ext_vector_type(2)));
typedef float  f32x4 __attribute__((ext_vector_type(4)));
typedef short  s16x4 __attribute__((ext_vector_type(4)));
typedef short  s16x8 __attribute__((ext_vector_type(8)));

static __device__ __forceinline__ unsigned short f2bf(float f){
    union { float f; unsigned u; } x; x.f = f;
    unsigned r = x.u + 0x7FFFu + ((x.u >> 16) & 1u);   // round-to-nearest-even
    return (unsigned short)(r >> 16);
}
static __device__ __forceinline__ unsigned packbf(float lo, float hi){
    unsigned r;
    asm("v_cvt_pk_bf16_f32 %0, %1, %2" : "=v"(r) : "v"(lo), "v"(hi));
    return r;
}
static __device__ __forceinline__ void pkfma(f32x2& acc, f32x2 c, f32x2 vv){
    asm("v_pk_fma_f32 %0, %1, %2, %0" : "+v"(acc) : "v"(c), "v"(vv));
}
#define BLO(u) __uint_as_float((u) << 16)
#define BHI(u) __uint_as_float((u) & 0xFFFF0000u)

// ---------------- graph prep ----------------
__global__ void k_hist(const int* __restrict__ rows, int* __restrict__ counts){
    int e = blockIdx.x * 256 + threadIdx.x;
    if (e < NNZ_N) atomicAdd(&counts[rows[e]], 1);
}
__global__ void k_deghist(const int* __restrict__ counts, int* __restrict__ dh){
    int v = blockIdx.x * 256 + threadIdx.x;
    if (v < V_N){ int d = counts[v]; if (d > 63) d = 63; atomicAdd(&dh[d], 1); }
}
__global__ void k_degscan(const int* __restrict__ dh, int* __restrict__ dhoff){
    if (threadIdx.x == 0){ int s = 0; for (int i = 0; i < 64; ++i){ dhoff[i] = s; s += dh[i]; } }
}
__global__ void k_sortrows(const int* __restrict__ counts, int* __restrict__ dhoff,
                           int* __restrict__ row_order, int* __restrict__ sp,
                           int* __restrict__ counts2){
    int v = blockIdx.x * 256 + threadIdx.x;
    if (v < V_N){
        int d = counts[v]; int db = d > 63 ? 63 : d;
        int pos = atomicAdd(&dhoff[db], 1);
        row_order[pos] = v; sp[v] = pos; counts2[pos] = d;
    }
}
// 64 groups of 64 sorted rows; slots/row = group max (clamped 64) + 3 pad rows (zeros)
__global__ void k_goff(const int* __restrict__ counts2, int* __restrict__ gcnt,
                       int* __restrict__ goff){
    if (threadIdx.x == 0){
        int off = 0;
        for (int g = 0; g < 64; ++g){
            int d = counts2[g * 64 + 63];
            if (d > 64) d = 64;
            gcnt[g] = d; goff[g] = off; off += (d + 3) * 64;
        }
    }
}
// lane-transposed zero-padded ELL: slot(g, i, lane) = goff[g] + i*64 + lane
// entry = (col*16) | (bf16(val) << 16)   -- low16 is the T4 byte offset
__global__ void k_fillell(const int* __restrict__ rows, const int* __restrict__ cols,
                          const float* __restrict__ vals, const int* __restrict__ sp,
                          const int* __restrict__ gcnt, const int* __restrict__ goff,
                          int* __restrict__ rcur, unsigned* __restrict__ ell){
    int e = blockIdx.x * 256 + threadIdx.x;
    if (e < NNZ_N){
        int r = rows[e]; int s = sp[r]; int g = s >> 6; int l = s & 63;
        int i = atomicAdd(&rcur[r], 1);
        if (i < gcnt[g])
            ell[goff[g] + i * 64 + l] =
                ((unsigned)cols[e] << 4) | ((unsigned)f2bf(vals[e]) << 16);
    }
}
// W packed into MFMA B-fragment order
__global__ void k_wtab(const float* __restrict__ w, unsigned short* __restrict__ wtab){
    int idx = blockIdx.x * 256 + threadIdx.x;   // 0..8191
    int slot = idx >> 3, j = idx & 7;
    int ki = slot >> 7, nh = (slot >> 6) & 1, l = slot & 63;
    int p  = ki * 32 + ((l >> 4) << 3) + j;
    int fo = nh * 16 + (l & 15);
    wtab[idx] = f2bf(w[p * 32 + fo]);
}

// ---------------- k_pre: input transpose -> t0 planes (bf16), ALL stl once --------
// block = (f, vblk of 64 v). t0 layout: t0[(stl*32 + f)*4096 + v] (uint4 = 8 sl)
__global__ __launch_bounds__(256, 4) void k_pre(
    const float* __restrict__ in, uint4* __restrict__ t0)
{
    __shared__ unsigned short lds[64 * 218];   // 27.3 KB, row stride 436 B
    int bid = blockIdx.x;
    int f = bid >> 6, vblk = bid & 63;
    int t = threadIdx.x;
    const f32x4* src = (const f32x4*)(in + ((size_t)f * V_N + vblk * 64) * S_N);

    #pragma unroll
    for (int it = 0; it < 14; ++it){
        int idx = t + it * 256;                 // float4 index, 0..3455
        if (idx < 3456){
            int vloc = (int)(((unsigned)idx * 4855u) >> 18);   // idx / 54
            int s4   = idx - vloc * 54;
            f32x4 a = __builtin_nontemporal_load(&src[idx]);
            uint2 q; q.x = packbf(a.x, a.y); q.y = packbf(a.z, a.w);
            *(uint2*)((char*)lds + vloc * 436 + s4 * 8) = q;
        }
    }
    __syncthreads();
    #pragma unroll
    for (int it = 0; it < 7; ++it){
        int idx = t + it * 256;
        if (idx < ST_TOT * 64){
            int stl = idx >> 6, vl = idx & 63;
            uint4 q = *(const uint4*)((const char*)lds + vl * 436 + stl * 16);
            t0[(((size_t)(stl * 32 + f)) << 12) + vblk * 64 + vl] = q;
        }
    }
}

// ---------------- Phase A: LDS-resident Chebyshev recurrence ----------------
// basis (chunk-local): basis[(stl*256 + p)*4096 + v]
__global__ __launch_bounds__(1024, 8) void k_phaseA(
    const int* __restrict__ row_order,
    const int* __restrict__ goff, const int* __restrict__ gcnt,
    const unsigned* __restrict__ ell, const uint4* __restrict__ t0,
    uint4* __restrict__ basis, int st0)
{
    __shared__ uint4 T4[V_N];        // 64 KB
    int f   = blockIdx.x & 31;
    int stl = blockIdx.x >> 5;       // chunk-local
    int st_g = st0 + stl;            // global
    int t = threadIdx.x;

    // T0 from t0 (coalesced 64 KB read) -> LDS + basis k=0 plane
    const uint4* t0p = t0 + (((size_t)(st_g * 32 + f)) << 12);
    uint4* b0p = basis + (((size_t)(stl * 256 + f)) << 12);
    #pragma unroll
    for (int rr = 0; rr < 4; ++rr){
        int v = t + rr * 1024;
        uint4 q = t0p[v];
        T4[v] = q;
        b0p[v] = q;
    }
    __syncthreads();

    // wave w owns groups {w, w+16, w+32, w+48}  (strided => balanced degrees)
    int w = t >> 6, lane = t & 63;
    int vr[4], gba[4], gcn[4];
    #pragma unroll
    for (int rr = 0; rr < 4; ++rr){
        int g = w + rr * 16;
        vr[rr]  = row_order[g * 64 + lane];
        gba[rr] = goff[g] + lane;
        gcn[rr] = __builtin_amdgcn_readfirstlane(gcnt[g]);
    }
    uint4 tm2[4];
    #pragma unroll
    for (int rr = 0; rr < 4; ++rr) tm2[rr] = T4[vr[rr]];   // T0 own rows

    for (int k = 1; k < 8; ++k){
        uint4 nst[4];
        #pragma unroll
        for (int rr = 0; rr < 4; ++rr){
            f32x2 ac0 = {0,0}, ac1 = {0,0}, ac2 = {0,0}, ac3 = {0,0};
            const unsigned* ep = ell + gba[rr];
            int cnt = gcn[rr];
            unsigned u0 = ep[0];
            unsigned u1 = ep[64];
            for (int i = 0; i < cnt; i += 2){
                unsigned n0 = ep[(i + 2) << 6];     // prefetch next pair (pad rows are 0)
                unsigned n1 = ep[(i + 3) << 6];
                uint4 q0 = *(const uint4*)((const char*)T4 + (u0 & 0xFFF0u));
                uint4 q1 = *(const uint4*)((const char*)T4 + (u1 & 0xFFF0u));
                float v0 = __uint_as_float(u0 & 0xFFFF0000u);
                float v1 = __uint_as_float(u1 & 0xFFFF0000u);
                f32x2 vv0 = {v0, v0};
                f32x2 vv1 = {v1, v1};
                f32x2 c;
                c.x = BLO(q0.x); c.y = BHI(q0.x);  pkfma(ac0, c, vv0);
                c.x = BLO(q0.y); c.y = BHI(q0.y);  pkfma(ac1, c, vv0);
                c.x = BLO(q0.z); c.y = BHI(q0.z);  pkfma(ac2, c, vv0);
                c.x = BLO(q0.w); c.y = BHI(q0.w);  pkfma(ac3, c, vv0);
                c.x = BLO(q1.x); c.y = BHI(q1.x);  pkfma(ac0, c, vv1);
                c.x = BLO(q1.y); c.y = BHI(q1.y);  pkfma(ac1, c, vv1);
                c.x = BLO(q1.z); c.y = BHI(q1.z);  pkfma(ac2, c, vv1);
                c.x = BLO(q1.w); c.y = BHI(q1.w);  pkfma(ac3, c, vv1);
                u0 = n0; u1 = n1;
            }
            float a0 = ac0.x, a1 = ac0.y, a2 = ac1.x, a3 = ac1.y;
            float a4 = ac2.x, a5 = ac2.y, a6 = ac3.x, a7 = ac3.y;
            if (k > 1){
                a0 = fmaf(2.f, a0, -BLO(tm2[rr].x));  a1 = fmaf(2.f, a1, -BHI(tm2[rr].x));
                a2 = fmaf(2.f, a2, -BLO(tm2[rr].y));  a3 = fmaf(2.f, a3, -BHI(tm2[rr].y));
                a4 = fmaf(2.f, a4, -BLO(tm2[rr].z));  a5 = fmaf(2.f, a5, -BHI(tm2[rr].z));
                a6 = fmaf(2.f, a6, -BLO(tm2[rr].w));  a7 = fmaf(2.f, a7, -BHI(tm2[rr].w));
            }
            nst[rr].x = packbf(a0, a1); nst[rr].y = packbf(a2, a3);
            nst[rr].z = packbf(a4, a5); nst[rr].w = packbf(a6, a7);
        }
        #pragma unroll
        for (int rr = 0; rr < 4; ++rr) tm2[rr] = T4[vr[rr]];   // T_{k-1} own rows
        __syncthreads();
        #pragma unroll
        for (int rr = 0; rr < 4; ++rr) T4[vr[rr]] = nst[rr];   // LDS <- T_k
        __syncthreads();
        // coalesced basis write of T_k from LDS (natural row order)
        size_t pb = ((size_t)(stl * 256 + k * 32 + f)) << 12;
        #pragma unroll
        for (int rr = 0; rr < 4; ++rr){
            int v = t + rr * 1024;
            basis[pb + v] = T4[v];
        }
    }
}

// ---------------- Phase B: projection GEMM (MFMA bf16), 128 rows/block ----------------
__global__ __launch_bounds__(256, 2) void k_phaseB(
    const uint4* __restrict__ basis, const uint4* __restrict__ wtab,
    const float* __restrict__ bias, float* __restrict__ out, int st0)
{
    __shared__ uint4 AW[5120];   // A: 4096 uint4 (64 KB) + W: 1024 uint4 (16 KB)
    int t = threadIdx.x;
    int tile = blockIdx.x;            // chunk-local: stl = tile>>8, vblk = tile&255
    int stl = tile >> 8, vblk = tile & 255;
    const uint4* gA = basis + ((size_t)stl << 20) + (vblk << 4);

    // coalesced global read (16 lanes x 16B per plane) + permuted ds_write for tr_b16
    #pragma unroll
    for (int it = 0; it < 16; ++it){
        int g = (it << 8) + t;
        int p = g >> 4, vrr = g & 15;
        uint4 q = gA[((size_t)p << 12) + vrr];
        int b = ((vrr >> 2) << 10) + (((vrr >> 1) & 1) << 9)
              + ((p >> 5) << 6) + (((p >> 2) & 1) << 5) + (((p >> 3) & 3) << 3)
              + ((p & 3) << 1) + (vrr & 1);
        AW[b] = q;
    }
    #pragma unroll
    for (int it = 0; it < 4; ++it)  AW[4096 + (it << 8) + t] = wtab[(it << 8) + t];
    __syncthreads();

    int lane = t & 63, w = t >> 6;
    unsigned ldsA = (unsigned)(size_t)(&AW[0]);
    unsigned abase = ldsA + w * 16384 + (lane << 3);
    const char* wbase = (const char*)&AW[4096];

    f32x4 acc00 = {0,0,0,0}, acc01 = {0,0,0,0}, acc10 = {0,0,0,0}, acc11 = {0,0,0,0};
    #pragma unroll
    for (int ki = 0; ki < 8; ++ki){
        s16x4 x0, x1, x2, x3;
        unsigned a0 = abase + (ki << 10);
        unsigned a1 = a0 + 8192;
        asm volatile("ds_read_b64_tr_b16 %0, %4\n\t"
                     "ds_read_b64_tr_b16 %1, %4 offset:512\n\t"
                     "ds_read_b64_tr_b16 %2, %5\n\t"
                     "ds_read_b64_tr_b16 %3, %5 offset:512\n\t"
                     "s_waitcnt lgkmcnt(0)"
                     : "=&v"(x0), "=&v"(x1), "=&v"(x2), "=&v"(x3)
                     : "v"(a0), "v"(a1));
        __builtin_amdgcn_sched_barrier(0);
        s16x8 af0, af1;
        af0[0]=x0[0]; af0[1]=x0[1]; af0[2]=x0[2]; af0[3]=x0[3];
        af0[4]=x1[0]; af0[5]=x1[1]; af0[6]=x1[2]; af0[7]=x1[3];
        af1[0]=x2[0]; af1[1]=x2[1]; af1[2]=x2[2]; af1[3]=x2[3];
        af1[4]=x3[0]; af1[5]=x3[1]; af1[6]=x3[2]; af1[7]=x3[3];
        s16x8 b0 = *(const s16x8*)(wbase + (((ki * 2 + 0) * 64 + lane) << 4));
        s16x8 b1 = *(const s16x8*)(wbase + (((ki * 2 + 1) * 64 + lane) << 4));
        acc00 = __builtin_amdgcn_mfma_f32_16x16x32_bf16(af0, b0, acc00, 0, 0, 0);
        acc01 = __builtin_amdgcn_mfma_f32_16x16x32_bf16(af0, b1, acc01, 0, 0, 0);
        acc10 = __builtin_amdgcn_mfma_f32_16x16x32_bf16(af1, b0, acc10, 0, 0, 0);
        acc11 = __builtin_amdgcn_mfma_f32_16x16x32_bf16(af1, b1, acc11, 0, 0, 0);
    }

    // stage output tile in LDS (reuse A region), then fully-coalesced global store
    __syncthreads();
    float* outT = (float*)&AW[0];     // layout [fo][132] floats
    {
        int rl0 = w * 32 + ((lane >> 4) << 2);
        int foA = (lane & 15), foB = 16 + (lane & 15);
        float2 p;
        p.x = acc00[0]; p.y = acc00[1]; *(float2*)&outT[foA*132 + rl0]      = p;
        p.x = acc00[2]; p.y = acc00[3]; *(float2*)&outT[foA*132 + rl0 + 2]  = p;
        p.x = acc01[0]; p.y = acc01[1]; *(float2*)&outT[foB*132 + rl0]      = p;
        p.x = acc01[2]; p.y = acc01[3]; *(float2*)&outT[foB*132 + rl0 + 2]  = p;
        p.x = acc10[0]; p.y = acc10[1]; *(float2*)&outT[foA*132 + rl0 + 16] = p;
        p.x = acc10[2]; p.y = acc10[3]; *(float2*)&outT[foA*132 + rl0 + 18] = p;
        p.x = acc11[0]; p.y = acc11[1]; *(float2*)&outT[foB*132 + rl0 + 16] = p;
        p.x = acc11[2]; p.y = acc11[3]; *(float2*)&outT[foB*132 + rl0 + 18] = p;
    }
    __syncthreads();
    {
        int fo = t >> 3;
        float bs = bias[fo];
        float* gb = out + (size_t)fo * V_N * S_N;
        #pragma unroll
        for (int it = 0; it < 4; ++it){
            int rl = ((t & 7) << 2) + (it << 5);
            float2 p0 = *(const float2*)&outT[fo*132 + rl];
            float2 p1 = *(const float2*)&outT[fo*132 + rl + 2];
            int r = tile * 128 + rl;
            int st = st0 + (r >> 15), rem = r & 32767;
            int v = rem >> 3, sl = rem & 7;
            f32x4 o; o.x = p0.x + bs; o.y = p0.y + bs; o.z = p1.x + bs; o.w = p1.y + bs;
            __builtin_nontemporal_store(o, (f32x4*)(gb + (size_t)v * S_N + st * 8 + sl));
        }
    }
}

// ---------------- host ----------------
extern "C" void kernel_launch(void* const* d_in, const int* in_sizes, int n_in,
                              void* d_out, int out_size, void* d_ws, size_t ws_size,
                              hipStream_t stream)
{
    const float* inp  = (const float*)d_in[0];
    const float* wgt  = (const float*)d_in[1];
    const float* bias = (const float*)d_in[2];
    const float* vals = (const float*)d_in[3];
    const int*   rows = (const int*)d_in[4];
    const int*   cols = (const int*)d_in[5];
    float* out = (float*)d_out;

    char* ws = (char*)d_ws;
    size_t o = 0;
    auto alloc = [&](size_t bytes) -> void* {
        void* p = ws + o; o = (o + bytes + 255) & ~(size_t)255; return p;
    };
    const size_t ELL_B = (size_t)64 * 67 * 64 * 4;   // 1.05 MB hard cap
    int* counts    = (int*)alloc(4096 * 4);
    int* dh        = (int*)alloc(64 * 4);
    int* dhoff     = (int*)alloc(64 * 4);
    int* row_order = (int*)alloc(4096 * 4);
    int* sp        = (int*)alloc(4096 * 4);
    int* counts2   = (int*)alloc(4096 * 4);
    int* gcnt      = (int*)alloc(64 * 4);
    int* goff      = (int*)alloc(64 * 4);
    int* rcur      = (int*)alloc(4096 * 4);
    unsigned* ell  = (unsigned*)alloc(ELL_B);
    uint4* wtab    = (uint4*)alloc(8192 * 2);
    uint4* t0buf   = (uint4*)alloc((size_t)ST_TOT * 32 * V_N * 16);   // 56.6 MB
    size_t used = o;

    size_t per_st = (size_t)PLANES * V_N * 16;       // 16.78 MB per s8-tile
    size_t avail = (ws_size > used) ? (ws_size - used) : 0;
    int tiles_c = (int)(avail / per_st);
    if (tiles_c > 16) tiles_c = 16;                  // {16,11} chunk pattern target
    if (tiles_c < 1) tiles_c = 1;
    uint4* basis = (uint4*)alloc(per_st * tiles_c);  // chunk-local, region-reused

    hipMemsetAsync(counts, 0, 4096 * 4, stream);
    hipMemsetAsync(dh, 0, 64 * 4, stream);
    hipMemsetAsync(rcur, 0, 4096 * 4, stream);
    hipMemsetAsync(ell, 0, ELL_B, stream);
    k_hist    <<<144, 256, 0, stream>>>(rows, counts);
    k_deghist <<<16, 256, 0, stream>>>(counts, dh);
    k_degscan <<<1, 64, 0, stream>>>(dh, dhoff);
    k_sortrows<<<16, 256, 0, stream>>>(counts, dhoff, row_order, sp, counts2);
    k_goff    <<<1, 64, 0, stream>>>(counts2, gcnt, goff);
    k_fillell <<<144, 256, 0, stream>>>(rows, cols, vals, sp, gcnt, goff, rcur, ell);
    k_wtab    <<<32, 256, 0, stream>>>(wgt, (unsigned short*)wtab);
    k_pre     <<<2048, 256, 0, stream>>>(inp, t0buf);

    for (int st0 = 0; st0 < ST_TOT; st0 += tiles_c){
        int tc = ST_TOT - st0; if (tc > tiles_c) tc = tiles_c;
        k_phaseA<<<32 * tc, 1024, 0, stream>>>(row_order, goff, gcnt, ell, t0buf, basis, st0);
        k_phaseB<<<tc * 256, 256, 0, stream>>>(basis, wtab, bias, out, st0);
    }
}